// Round 2
// baseline (650.894 us; speedup 1.0000x reference)
//
#include <hip/hip_runtime.h>
#include <hip/hip_bf16.h>
#include <stdint.h>
#include <stddef.h>

// Problem constants (from reference setup_inputs)
#define N_NODES 8192
#define DIM     256
#define BATCH   4096
#define CLASSES 1000
#define ALPHA_C 1.0f
#define BETA_C  0.01f
#define GAMMA_C 0.1f
#define COS_EPS 1e-8f

typedef __bf16 bf16_t;
typedef __bf16 bf16x8 __attribute__((ext_vector_type(8)));
typedef float  f32x4  __attribute__((ext_vector_type(4)));

// ---------------------------------------------------------------------------
// Prep: per-row L2 norm (fp32) + bf16 cast of embeddings into workspace.
// ---------------------------------------------------------------------------
__global__ __launch_bounds__(256) void prep_kernel(
    const float* __restrict__ emb, bf16_t* __restrict__ U,
    float* __restrict__ norms) {
  const int row = blockIdx.x;
  const int t = threadIdx.x;
  float v = emb[(size_t)row * DIM + t];
  U[(size_t)row * DIM + t] = (bf16_t)v;
  float sq = v * v;
  for (int off = 32; off; off >>= 1) sq += __shfl_down(sq, off);
  __shared__ float red[4];
  const int wave = t >> 6, lane = t & 63;
  if (lane == 0) red[wave] = sq;
  __syncthreads();
  if (t == 0) {
    float s = red[0] + red[1] + red[2] + red[3];
    norms[row] = sqrtf(s);
  }
}

// ---------------------------------------------------------------------------
// Cross-entropy: one block per batch row; SINGLE global pass — logits cached
// in registers (4/thread), max + sum-exp from regs.
// ---------------------------------------------------------------------------
__global__ __launch_bounds__(256) void ce_kernel(
    const float* __restrict__ pred, const int* __restrict__ target,
    float* __restrict__ out) {
  const int row = blockIdx.x;
  const int t = threadIdx.x;
  const float* p = pred + (size_t)row * CLASSES;

  float v[4];
  for (int k = 0; k < 4; ++k) {
    const int c = t + k * 256;
    v[k] = (c < CLASSES) ? p[c] : -INFINITY;
  }

  float m = fmaxf(fmaxf(v[0], v[1]), fmaxf(v[2], v[3]));
  for (int off = 32; off; off >>= 1) m = fmaxf(m, __shfl_down(m, off));

  __shared__ float red[8];
  const int wave = t >> 6, lane = t & 63;
  if (lane == 0) red[wave] = m;
  __syncthreads();
  if (t == 0) red[4] = fmaxf(fmaxf(red[0], red[1]), fmaxf(red[2], red[3]));
  __syncthreads();
  const float mx = red[4];

  float s = 0.f;
  for (int k = 0; k < 4; ++k) s += __expf(v[k] - mx);  // exp(-inf)=0 for pads
  for (int off = 32; off; off >>= 1) s += __shfl_down(s, off);
  if (lane == 0) red[wave] = s;
  __syncthreads();
  if (t == 0) {
    float ssum = red[0] + red[1] + red[2] + red[3];
    float lse = mx + __logf(ssum);
    float loss = lse - p[target[row]];
    atomicAdd(out, loss * (ALPHA_C / (float)BATCH));
  }
}

// ---------------------------------------------------------------------------
// Fused Gram + weighted reduction, 128x128 block tile, BK=64 K-chunks.
//   out += sum [ BETA*|a| + GAMMA*a*(1 - dot/max(n_i*n_j,eps)) ] / N^2
// 4 waves, each owns a 64x64 sub-tile = 4x4 grid of 16x16x32 bf16 MFMAs.
// LDS row stride 72 elems (144 B): fragment ds_read_b128 conflict-free.
// Next K-chunk's global loads prefetched into registers during MFMA.
// ---------------------------------------------------------------------------
#define BT  128
#define BK  64
#define LDK 72

__global__ __launch_bounds__(256, 3) void gram_kernel(
    const float* __restrict__ adj, const bf16_t* __restrict__ U,
    const float* __restrict__ norms, float* __restrict__ out) {
  __shared__ __align__(16) bf16_t As[BT * LDK];
  __shared__ __align__(16) bf16_t Bs[BT * LDK];

  const int bi = blockIdx.y, bj = blockIdx.x;
  const int i0 = bi * BT, j0 = bj * BT;
  const int t = threadIdx.x;

  // Staging geometry: 8 threads/row x 16 B = 128 B (= BK bf16) per row,
  // 32 rows per pass, 4 passes for 128 rows.
  const int sr = t >> 3;        // 0..31
  const int sc = (t & 7) * 8;   // elem offset 0..56

  // Prefetch chunk 0 into registers.
  uint4 pa[4], pb[4];
  for (int pass = 0; pass < 4; ++pass) {
    const int r = pass * 32 + sr;
    pa[pass] = *(const uint4*)(U + (size_t)(i0 + r) * DIM + sc);
    pb[pass] = *(const uint4*)(U + (size_t)(j0 + r) * DIM + sc);
  }

  const int wave = t >> 6;
  const int lane = t & 63;
  const int wr = (wave >> 1) * 64;  // wave row offset in tile
  const int wc = (wave & 1) * 64;   // wave col offset
  const int fr = lane & 15;         // fragment m/n index
  const int fq = lane >> 4;         // quad: k-offset fq*8 (A/B), row fq*4 (C/D)

  f32x4 acc[4][4] = {};

  for (int kc = 0; kc < DIM / BK; ++kc) {
    // Write prefetched chunk to LDS.
    for (int pass = 0; pass < 4; ++pass) {
      const int r = pass * 32 + sr;
      *(uint4*)(&As[r * LDK + sc]) = pa[pass];
      *(uint4*)(&Bs[r * LDK + sc]) = pb[pass];
    }
    __syncthreads();

    // Prefetch next chunk while MFMAs run.
    if (kc + 1 < DIM / BK) {
      const int ko = (kc + 1) * BK;
      for (int pass = 0; pass < 4; ++pass) {
        const int r = pass * 32 + sr;
        pa[pass] = *(const uint4*)(U + (size_t)(i0 + r) * DIM + ko + sc);
        pb[pass] = *(const uint4*)(U + (size_t)(j0 + r) * DIM + ko + sc);
      }
    }

    for (int kk = 0; kk < BK; kk += 32) {
      bf16x8 a[4], b[4];
      for (int ms = 0; ms < 4; ++ms)
        a[ms] = *(const bf16x8*)(&As[(wr + ms * 16 + fr) * LDK + kk + fq * 8]);
      for (int ns = 0; ns < 4; ++ns)
        b[ns] = *(const bf16x8*)(&Bs[(wc + ns * 16 + fr) * LDK + kk + fq * 8]);
      for (int ms = 0; ms < 4; ++ms)
        for (int ns = 0; ns < 4; ++ns)
          acc[ms][ns] = __builtin_amdgcn_mfma_f32_16x16x32_bf16(
              a[ms], b[ns], acc[ms][ns], 0, 0, 0);
    }
    __syncthreads();
  }

  // Norms for my fragment rows/cols (L1/L2-cached broadcasts).
  float rn[4][4], cn[4];
  for (int ms = 0; ms < 4; ++ms)
    for (int r = 0; r < 4; ++r)
      rn[ms][r] = norms[i0 + wr + ms * 16 + fq * 4 + r];
  for (int ns = 0; ns < 4; ++ns) cn[ns] = norms[j0 + wc + ns * 16 + fr];

  // Epilogue: C/D layout col=lane&15, row=(lane>>4)*4+reg.
  float local = 0.f;
  for (int ms = 0; ms < 4; ++ms) {
    const int ibase = i0 + wr + ms * 16 + fq * 4;
    for (int ns = 0; ns < 4; ++ns) {
      const int jj = j0 + wc + ns * 16 + fr;
      for (int r = 0; r < 4; ++r) {
        const int ii = ibase + r;
        const float dot = acc[ms][ns][r];
        const float sim =
            dot * __builtin_amdgcn_rcpf(fmaxf(rn[ms][r] * cn[ns], COS_EPS));
        const float a = adj[(size_t)ii * N_NODES + jj];
        local += BETA_C * fabsf(a) + GAMMA_C * a * (1.f - sim);
      }
    }
  }

  for (int off = 32; off; off >>= 1) local += __shfl_down(local, off);
  __shared__ float red[4];
  if (lane == 0) red[wave] = local;
  __syncthreads();
  if (t == 0) {
    const float inv = 1.f / ((float)N_NODES * (float)N_NODES);
    atomicAdd(out, (red[0] + red[1] + red[2] + red[3]) * inv);
  }
}

// ---------------------------------------------------------------------------
extern "C" void kernel_launch(void* const* d_in, const int* in_sizes, int n_in,
                              void* d_out, int out_size, void* d_ws,
                              size_t ws_size, hipStream_t stream) {
  const float* pred   = (const float*)d_in[0];
  const int*   target = (const int*)d_in[1];
  const float* adj    = (const float*)d_in[2];
  const float* emb    = (const float*)d_in[3];
  float* out = (float*)d_out;

  bf16_t* U     = (bf16_t*)d_ws;
  float*  norms = (float*)((char*)d_ws + (size_t)N_NODES * DIM * sizeof(bf16_t));

  hipMemsetAsync(d_out, 0, sizeof(float), stream);
  prep_kernel<<<N_NODES, 256, 0, stream>>>(emb, U, norms);
  ce_kernel<<<BATCH, 256, 0, stream>>>(pred, target, out);
  gram_kernel<<<dim3(N_NODES / BT, N_NODES / BT), 256, 0, stream>>>(
      adj, U, norms, out);
}

// Round 3
// 471.278 us; speedup vs baseline: 1.3811x; 1.3811x over previous
//
#include <hip/hip_runtime.h>
#include <hip/hip_bf16.h>
#include <stdint.h>
#include <stddef.h>

// Problem constants (from reference setup_inputs)
#define N_NODES 8192
#define DIM     256
#define BATCH   4096
#define CLASSES 1000
#define ALPHA_C 1.0f
#define BETA_C  0.01f
#define GAMMA_C 0.1f

typedef __bf16 bf16_t;
typedef __bf16 bf16x8 __attribute__((ext_vector_type(8)));
typedef float  f32x4  __attribute__((ext_vector_type(4)));
typedef float  f32x16 __attribute__((ext_vector_type(16)));

// Async global->LDS DMA, 16 B/lane, dest = wave-uniform base + lane*16.
__device__ __forceinline__ void async16(const void* g, void* l) {
  __builtin_amdgcn_global_load_lds(
      (const __attribute__((address_space(1))) uint32_t*)g,
      (__attribute__((address_space(3))) uint32_t*)l, 16, 0, 0);
}

// ---------------------------------------------------------------------------
// Prep: L2-normalize each embedding row (fp32 math) and store bf16.
// Gram of normalized rows == cosine similarity; norms never needed again.
// ---------------------------------------------------------------------------
__global__ __launch_bounds__(256) void prep_kernel(
    const float* __restrict__ emb, bf16_t* __restrict__ U) {
  const int row = blockIdx.x;
  const int t = threadIdx.x;
  const float v = emb[(size_t)row * DIM + t];
  float sq = v * v;
  for (int off = 32; off; off >>= 1) sq += __shfl_down(sq, off);
  __shared__ float red[4];
  if ((t & 63) == 0) red[t >> 6] = sq;
  __syncthreads();
  const float total = red[0] + red[1] + red[2] + red[3];
  U[(size_t)row * DIM + t] = (bf16_t)(v * rsqrtf(total));
}

// ---------------------------------------------------------------------------
// Cross-entropy: one block per batch row; single global pass, logits in regs.
// ---------------------------------------------------------------------------
__global__ __launch_bounds__(256) void ce_kernel(
    const float* __restrict__ pred, const int* __restrict__ target,
    float* __restrict__ out) {
  const int row = blockIdx.x;
  const int t = threadIdx.x;
  const float* p = pred + (size_t)row * CLASSES;

  float v[4];
  for (int k = 0; k < 4; ++k) {
    const int c = t + k * 256;
    v[k] = (c < CLASSES) ? p[c] : -INFINITY;
  }

  float m = fmaxf(fmaxf(v[0], v[1]), fmaxf(v[2], v[3]));
  for (int off = 32; off; off >>= 1) m = fmaxf(m, __shfl_down(m, off));

  __shared__ float red[8];
  const int wave = t >> 6, lane = t & 63;
  if (lane == 0) red[wave] = m;
  __syncthreads();
  if (t == 0) red[4] = fmaxf(fmaxf(red[0], red[1]), fmaxf(red[2], red[3]));
  __syncthreads();
  const float mx = red[4];

  float s = 0.f;
  for (int k = 0; k < 4; ++k) s += __expf(v[k] - mx);
  for (int off = 32; off; off >>= 1) s += __shfl_down(s, off);
  if (lane == 0) red[wave] = s;
  __syncthreads();
  if (t == 0) {
    float ssum = red[0] + red[1] + red[2] + red[3];
    float lse = mx + __logf(ssum);
    float loss = lse - p[target[row]];
    atomicAdd(out, loss * (ALPHA_C / (float)BATCH));
  }
}

// ---------------------------------------------------------------------------
// Fused sim-Gram + adj-weighted reduction. BT=128, BK=64, 4 K-chunks.
//   out += sum [ BETA*|a_ji| + GAMMA*a_ji*(1 - sim_ij) ] / N^2   (sim symmetric)
// Staging: global_load_lds w=16 into XOR-swizzled [row][64] LDS (no padding,
//   chunk c of row R stored at position c^(R&7): b128 frag reads hit the
//   8-lane/bank structural minimum).
// Compute: 4 waves x (64x64 tile) = 2x2 of v_mfma_f32_32x32x16_bf16.
// Epilogue: acc -> LDS as simT (2 passes of 64 rows, stride 68 f32), then
//   each lane does 8 coalesced float4 adjT loads per pass + FMA reduce.
// ---------------------------------------------------------------------------
#define BT 128

__global__ __launch_bounds__(256, 3) void gram_kernel(
    const float* __restrict__ adj, const bf16_t* __restrict__ U,
    float* __restrict__ out) {
  __shared__ __align__(16) float lds_f[128 * 68];  // 34 KB: staging / simT
  __shared__ float red[4];
  bf16_t* As = (bf16_t*)lds_f;                // [128][64] bf16 = 16 KB
  bf16_t* Bs = ((bf16_t*)lds_f) + 128 * 64;   // [128][64] bf16 = 16 KB

  const int bi = blockIdx.y, bj = blockIdx.x;
  const int i0 = bi * BT, j0 = bj * BT;
  const int t = threadIdx.x;
  const int w = t >> 6, lane = t & 63;
  const int wr = (w >> 1) * 64, wc = (w & 1) * 64;
  const int m = lane & 31, h = lane >> 5;

  // Staging: lane -> (row srow, stored chunk lane&7) fetches global chunk
  // (lane&7)^srow so that LDS position p holds global chunk p^(R&7).
  const int srow = lane >> 3;
  const int schunk = (lane & 7) ^ srow;

  f32x16 acc[2][2] = {};

  for (int kc = 0; kc < 4; ++kc) {
    const int ko = kc * 64;
#pragma unroll
    for (int ii = 0; ii < 4; ++ii) {
      const int rbase = w * 32 + ii * 8;  // wave-uniform
      async16(U + (size_t)(i0 + rbase + srow) * DIM + ko + schunk * 8,
              &As[rbase * 64]);
      async16(U + (size_t)(j0 + rbase + srow) * DIM + ko + schunk * 8,
              &Bs[rbase * 64]);
    }
    __syncthreads();
#pragma unroll
    for (int kk = 0; kk < 64; kk += 16) {
      const int p = (((kk >> 3) + h) ^ (m & 7)) * 8;  // deswizzled position
      bf16x8 a0 = *(const bf16x8*)&As[(wr + m) * 64 + p];
      bf16x8 a1 = *(const bf16x8*)&As[(wr + 32 + m) * 64 + p];
      bf16x8 b0 = *(const bf16x8*)&Bs[(wc + m) * 64 + p];
      bf16x8 b1 = *(const bf16x8*)&Bs[(wc + 32 + m) * 64 + p];
      acc[0][0] =
          __builtin_amdgcn_mfma_f32_32x32x16_bf16(a0, b0, acc[0][0], 0, 0, 0);
      acc[0][1] =
          __builtin_amdgcn_mfma_f32_32x32x16_bf16(a0, b1, acc[0][1], 0, 0, 0);
      acc[1][0] =
          __builtin_amdgcn_mfma_f32_32x32x16_bf16(a1, b0, acc[1][0], 0, 0, 0);
      acc[1][1] =
          __builtin_amdgcn_mfma_f32_32x32x16_bf16(a1, b1, acc[1][1], 0, 0, 0);
    }
    __syncthreads();
  }

  // Epilogue. C/D layout (32x32): col = lane&31, row = (reg&3)+8*(reg>>2)+4*h.
  // Pass ms covers 64 sim rows: {ms*32..ms*32+31} U {64+ms*32..64+ms*32+31}.
  float local = 0.f;
  const int g4 = t & 15;
  const int i_rel = ((g4 & 8) ? 64 : 0) + (g4 & 7) * 4;

#pragma unroll
  for (int ms = 0; ms < 2; ++ms) {
    // Write simT[col 0..127][row-in-pass 0..63], stride 68 (16B-aligned,
    // conflict-free b128 writes).
#pragma unroll
    for (int ns = 0; ns < 2; ++ns) {
      const int c = wc + ns * 32 + m;
#pragma unroll
      for (int rg = 0; rg < 4; ++rg) {
        const int rh = (w >> 1) * 32 + rg * 8 + h * 4;
        f32x4 vv = {acc[ms][ns][rg * 4 + 0], acc[ms][ns][rg * 4 + 1],
                    acc[ms][ns][rg * 4 + 2], acc[ms][ns][rg * 4 + 3]};
        *(f32x4*)&lds_f[c * 68 + rh] = vv;
      }
    }
    __syncthreads();
    const int i_off = ms * 32 + i_rel;
#pragma unroll
    for (int k = 0; k < 8; ++k) {
      const int c = (t >> 4) + k * 16;
      const f32x4 s = *(const f32x4*)&lds_f[c * 68 + g4 * 4];
      const float4 a4 =
          *(const float4*)&adj[(size_t)(j0 + c) * N_NODES + i0 + i_off];
      local +=
          BETA_C * (fabsf(a4.x) + fabsf(a4.y) + fabsf(a4.z) + fabsf(a4.w));
      local += GAMMA_C * (a4.x * (1.f - s.x) + a4.y * (1.f - s.y) +
                          a4.z * (1.f - s.z) + a4.w * (1.f - s.w));
    }
    __syncthreads();
  }

  for (int off = 32; off; off >>= 1) local += __shfl_down(local, off);
  if (lane == 0) red[w] = local;
  __syncthreads();
  if (t == 0) {
    const float inv = 1.f / ((float)N_NODES * (float)N_NODES);
    atomicAdd(out, (red[0] + red[1] + red[2] + red[3]) * inv);
  }
}

// ---------------------------------------------------------------------------
extern "C" void kernel_launch(void* const* d_in, const int* in_sizes, int n_in,
                              void* d_out, int out_size, void* d_ws,
                              size_t ws_size, hipStream_t stream) {
  const float* pred   = (const float*)d_in[0];
  const int*   target = (const int*)d_in[1];
  const float* adj    = (const float*)d_in[2];
  const float* emb    = (const float*)d_in[3];
  float* out = (float*)d_out;

  bf16_t* U = (bf16_t*)d_ws;  // 8192*256 bf16 = 4 MB (normalized rows)

  hipMemsetAsync(d_out, 0, sizeof(float), stream);
  prep_kernel<<<N_NODES, 256, 0, stream>>>(emb, U);
  ce_kernel<<<BATCH, 256, 0, stream>>>(pred, target, out);
  gram_kernel<<<dim3(N_NODES / BT, N_NODES / BT), 256, 0, stream>>>(adj, U,
                                                                    out);
}